// Round 1
// baseline (140.039 us; speedup 1.0000x reference)
//
#include <hip/hip_runtime.h>
#include <hip/hip_bf16.h>

// DeformConv2d: x[4,4,256,36,36] f32, filter[1024,256,3,3] f32, offset[16,2] f32
// out[4,1024,36,36] f32.
// Decomposition:
//   b = 16 samples; per (b,y,i): row-interp tables; per (b,x,j): col tables.
//   Xoff^T[b][p=y*36+x][k=c*9+i*3+j] bf16 (ws), W bf16 [1024][2304] (ws).
//   Then 16 GEMMs C_b[256,1296] = W_g[256,2304] * Xoff_b[2304,1296] via MFMA.
// ws requirement: (16*1296*2304 + 1024*2304)*2 = 100,270,080 bytes.

#define HH 36
#define WW 36
#define CT 256
#define NB 16
#define KK 2304      // CT*9
#define NP 1296      // HH*WW
#define OCH 1024
#define OUTG 256

typedef __attribute__((ext_vector_type(8))) short short8;
typedef __attribute__((ext_vector_type(4))) float f32x4;
typedef __attribute__((ext_vector_type(4))) unsigned short us4;

__device__ __forceinline__ unsigned short f2bf(float v) {
    unsigned u = __float_as_uint(v);
    u += 0x7fffu + ((u >> 16) & 1u);   // RNE, no NaN inputs expected
    return (unsigned short)(u >> 16);
}

// ---------------- kernel 1: filter fp32 -> bf16 (flat, layout already [och][k]) ----
__global__ __launch_bounds__(256) void cvt_filter(const float* __restrict__ f,
                                                  unsigned short* __restrict__ w) {
    int idx = (blockIdx.x * 256 + threadIdx.x) * 4;   // 2304 blocks covers 1024*2304
    float4 v = *reinterpret_cast<const float4*>(f + idx);
    us4 o;
    o.x = f2bf(v.x); o.y = f2bf(v.y); o.z = f2bf(v.z); o.w = f2bf(v.w);
    *reinterpret_cast<us4*>(w + idx) = o;
}

// ---------------- kernel 2: deformable bilinear sampling -> Xoff^T bf16 -----------
// block = (b, y), 256 threads. Writes xt[b][y*36+x][c*9+n] for all x,c,n.
__global__ __launch_bounds__(256) void sample_kernel(const float* __restrict__ x,
                                                     const float* __restrict__ off,
                                                     unsigned short* __restrict__ xt) {
    const int b = blockIdx.x / HH;
    const int y = blockIdx.x % HH;
    const int tid = threadIdx.x;
    const float sx = 3.0f / off[2 * b + 0];
    const float sy = 3.0f / off[2 * b + 1];

    // row (i) tables: block-uniform, computed redundantly per thread
    int qxl[3], qxr[3]; float gxl[3], gxr[3];
#pragma unroll
    for (int i = 0; i < 3; ++i) {
        float px = (float)(y + 1) + (float)(i - 1) * sx;
        float pc = fminf(fmaxf(px, 0.f), 37.f);
        float fl = floorf(px);
        float ql = fminf(fmaxf(fl, 0.f), 37.f);
        float qr = fminf(fmaxf(fl + 1.f, 0.f), 37.f);
        qxl[i] = (int)ql; qxr[i] = (int)qr;
        gxl[i] = 1.f + (ql - pc);
        gxr[i] = 1.f - (qr - pc);
    }

    // column (x,j) tables in LDS
    __shared__ int   s_qyl[HH * 3], s_qyr[HH * 3];
    __shared__ float s_gyl[HH * 3], s_gyr[HH * 3];
    if (tid < HH * 3) {
        int xx = tid / 3, j = tid % 3;
        float py = (float)(xx + 1) + (float)(j - 1) * sy;
        float pc = fminf(fmaxf(py, 0.f), 37.f);
        float fl = floorf(py);
        float ql = fminf(fmaxf(fl, 0.f), 37.f);
        float qr = fminf(fmaxf(fl + 1.f, 0.f), 37.f);
        s_qyl[tid] = (int)ql; s_qyr[tid] = (int)qr;
        s_gyl[tid] = 1.f + (ql - pc);
        s_gyr[tid] = 1.f - (qr - pc);
    }

    // row-interpolated values: xrow[c(64)][i(3)][col(38)] pitch 115 (odd -> no bank conflict)
    __shared__ float xrow[64 * 115];

    const float* xb = x + (size_t)b * CT * (HH * WW);

    for (int c0 = 0; c0 < CT; c0 += 64) {
        __syncthreads();   // also covers table init on first iteration
        for (int e = tid; e < 64 * 114; e += 256) {
            int c = e / 114;
            int rem = e - c * 114;
            int i = rem / 38;
            int col = rem - i * 38;          // padded column 0..37
            const float* xc = xb + (size_t)(c0 + c) * (HH * WW);
            float vl = 0.f, vr = 0.f;
            if (col >= 1 && col <= 36) {
                int rl = qxl[i], rr = qxr[i];
                if (rl >= 1 && rl <= 36) vl = xc[(rl - 1) * WW + (col - 1)];
                if (rr >= 1 && rr <= 36) vr = xc[(rr - 1) * WW + (col - 1)];
            }
            xrow[c * 115 + i * 38 + col] = gxl[i] * vl + gxr[i] * vr;
        }
        __syncthreads();
        const int wave = tid >> 6;
        const int c = tid & 63;
        for (int xi = wave; xi < HH; xi += 4) {
            size_t obase = ((size_t)(b * NP + y * WW + xi)) * KK + (size_t)(c0 + c) * 9;
#pragma unroll
            for (int n = 0; n < 9; ++n) {
                int i = n / 3, j = n - i * 3;
                int t = xi * 3 + j;
                float v = s_gyl[t] * xrow[c * 115 + i * 38 + s_qyl[t]]
                        + s_gyr[t] * xrow[c * 115 + i * 38 + s_qyr[t]];
                xt[obase + n] = f2bf(v);
            }
        }
    }
}

// ---------------- kernel 3: MFMA GEMM, 128x128 tile, BK=64, 4 waves ---------------
__global__ __launch_bounds__(256) void gemm_kernel(const unsigned short* __restrict__ wbf,
                                                   const unsigned short* __restrict__ xt,
                                                   float* __restrict__ out) {
    const int bx = blockIdx.x;        // 16 * 2 * 11 = 352 blocks
    const int b = bx / 22;
    const int rem = bx % 22;
    const int mt = rem / 11;
    const int nt = rem % 11;
    const int m0 = mt * 128;
    const int p0 = nt * 128;
    const int g = b & 3;
    const int mimg = b >> 2;

    const unsigned short* Ab = wbf + (size_t)(g * OUTG + m0) * KK;
    const unsigned short* Bb = xt + (size_t)b * NP * KK;

    __shared__ __align__(16) unsigned short As[128 * 64];
    __shared__ __align__(16) unsigned short Bs[128 * 64];

    const int tid = threadIdx.x;
    const int wave = tid >> 6, lane = tid & 63;
    const int wr = wave >> 1, wc = wave & 1;
    const int l8 = lane >> 3, ls = lane & 7;

    f32x4 acc[4][4] = {};

    for (int kt = 0; kt < 36; ++kt) {
        const int k0 = kt * 64;
        __syncthreads();
#pragma unroll
        for (int ii = 0; ii < 4; ++ii) {
            int inst = wave * 4 + ii;
            int row = inst * 8 + l8;                       // 0..127
            const unsigned short* srcA = Ab + (size_t)row * KK + k0 + ls * 8;
            __builtin_amdgcn_global_load_lds(
                (const __attribute__((address_space(1))) void*)srcA,
                (__attribute__((address_space(3))) void*)&As[inst * 512], 16, 0, 0);
            int prow = p0 + inst * 8 + l8;
            prow = prow < NP ? prow : NP - 1;              // clamp edge tile (masked at store)
            const unsigned short* srcB = Bb + (size_t)prow * KK + k0 + ls * 8;
            __builtin_amdgcn_global_load_lds(
                (const __attribute__((address_space(1))) void*)srcB,
                (__attribute__((address_space(3))) void*)&Bs[inst * 512], 16, 0, 0);
        }
        __syncthreads();
#pragma unroll
        for (int kk = 0; kk < 2; ++kk) {
            short8 a[4], bfr[4];
            const int krd = kk * 32 + (lane >> 4) * 8;
            const int rA = wr * 64 + (lane & 15);
            const int rB = wc * 64 + (lane & 15);
#pragma unroll
            for (int m = 0; m < 4; ++m)
                a[m] = *(const short8*)&As[(rA + m * 16) * 64 + krd];
#pragma unroll
            for (int n = 0; n < 4; ++n)
                bfr[n] = *(const short8*)&Bs[(rB + n * 16) * 64 + krd];
#pragma unroll
            for (int m = 0; m < 4; ++m)
#pragma unroll
                for (int n = 0; n < 4; ++n)
                    acc[m][n] = __builtin_amdgcn_mfma_f32_16x16x32_bf16(
                        a[m], bfr[n], acc[m][n], 0, 0, 0);
        }
    }

    float* ob = out + ((size_t)mimg * OCH + g * OUTG) * NP;
    const int o0 = m0 + wr * 64 + ((lane >> 4) << 2);
    const int pc = p0 + wc * 64 + (lane & 15);
#pragma unroll
    for (int n = 0; n < 4; ++n) {
        int p = pc + n * 16;
        if (p >= NP) continue;
#pragma unroll
        for (int m = 0; m < 4; ++m) {
#pragma unroll
            for (int r = 0; r < 4; ++r)
                ob[(size_t)(o0 + m * 16 + r) * NP + p] = acc[m][n][r];
        }
    }
}

extern "C" void kernel_launch(void* const* d_in, const int* in_sizes, int n_in,
                              void* d_out, int out_size, void* d_ws, size_t ws_size,
                              hipStream_t stream) {
    const float* x   = (const float*)d_in[0];
    const float* tf  = (const float*)d_in[1];
    const float* off = (const float*)d_in[2];
    float* out = (float*)d_out;

    unsigned short* xt  = (unsigned short*)d_ws;                    // [16][1296][2304] bf16
    unsigned short* wbf = xt + (size_t)NB * NP * KK;                // [1024][2304] bf16

    hipLaunchKernelGGL(cvt_filter, dim3((OCH * KK) / (256 * 4)), dim3(256), 0, stream, tf, wbf);
    hipLaunchKernelGGL(sample_kernel, dim3(NB * HH), dim3(256), 0, stream, x, off, xt);
    hipLaunchKernelGGL(gemm_kernel, dim3(352), dim3(256), 0, stream, wbf, xt, out);
}

// Round 2
// 103.094 us; speedup vs baseline: 1.3584x; 1.3584x over previous
//
#include <hip/hip_runtime.h>
#include <hip/hip_bf16.h>

// DeformConv2d: x[4,4,256,36,36] f32, filter[1024,256,3,3] f32, offset[16,2] f32
// out[4,1024,36,36] f32.
// K-axis layout (both operands, opaque to GEMM): k' = n*256 + c  (tap-major).
//   -> sample kernel writes 8B us4 stores (4 channels/tap), fully coalesced.
// ws: xt [16][1296][2304] bf16 + w' [1024][2304] bf16 = 100,270,080 B.

#define HH 36
#define WW 36
#define CT 256
#define NB 16
#define KK 2304      // 9*256
#define NP 1296      // 36*36
#define OCH 1024
#define OUTG 256

typedef __attribute__((ext_vector_type(8))) short short8;
typedef __attribute__((ext_vector_type(4))) float f32x4;
typedef __attribute__((ext_vector_type(4))) unsigned short us4;

__device__ __forceinline__ unsigned short f2bf(float v) {
    unsigned u = __float_as_uint(v);
    u += 0x7fffu + ((u >> 16) & 1u);   // RNE
    return (unsigned short)(u >> 16);
}

// ---------------- kernel 1: filter fp32 [o][c*9+n] -> bf16 [o][n*256+c] ----------
__global__ __launch_bounds__(256) void cvt_filter(const float* __restrict__ f,
                                                  unsigned short* __restrict__ w) {
    const int o = blockIdx.x;
    const float* fo = f + (size_t)o * KK;
    unsigned short* wo = w + (size_t)o * KK;
    for (int k4 = threadIdx.x * 4; k4 < KK; k4 += 1024) {
        int n = k4 >> 8;          // tap
        int c = k4 & 255;         // channel (multiple of 4)
        us4 v;
#pragma unroll
        for (int cc = 0; cc < 4; ++cc) v[cc] = f2bf(fo[(c + cc) * 9 + n]);
        *reinterpret_cast<us4*>(wo + k4) = v;
    }
}

// ---------------- kernel 2: deformable bilinear sampling -> Xoff^T bf16 -----------
// grid 2304 = 16b * 4chunk * 36y (XCD-swizzled); block handles 64 channels, one y.
__global__ __launch_bounds__(256) void sample_kernel(const float* __restrict__ x,
                                                     const float* __restrict__ off,
                                                     unsigned short* __restrict__ xt) {
    // bijective XCD swizzle: each XCD gets 288 consecutive work ids = 2 b's
    const int wid = (blockIdx.x & 7) * 288 + (blockIdx.x >> 3);
    const int b = wid / 144;
    const int rem = wid - b * 144;
    const int chunk = rem / 36;
    const int y = rem - chunk * 36;
    const int c0 = chunk * 64;
    const int tid = threadIdx.x;
    const float sx = 3.0f / off[2 * b + 0];
    const float sy = 3.0f / off[2 * b + 1];

    // row (i) tables: per-thread registers (block-uniform)
    int qxl[3], qxr[3]; float gxl[3], gxr[3];
#pragma unroll
    for (int i = 0; i < 3; ++i) {
        float px = (float)(y + 1) + (float)(i - 1) * sx;
        float pc = fminf(fmaxf(px, 0.f), 37.f);
        float fl = floorf(px);
        float ql = fminf(fmaxf(fl, 0.f), 37.f);
        float qr = fminf(fmaxf(fl + 1.f, 0.f), 37.f);
        qxl[i] = (int)ql; qxr[i] = (int)qr;
        gxl[i] = 1.f + (ql - pc);
        gxr[i] = 1.f - (qr - pc);
    }

    // column (x,j) tables in LDS
    __shared__ int   s_qyl[HH * 3], s_qyr[HH * 3];
    __shared__ float s_gyl[HH * 3], s_gyr[HH * 3];
    if (tid < HH * 3) {
        int xx = tid / 3, j = tid % 3;
        float py = (float)(xx + 1) + (float)(j - 1) * sy;
        float pc = fminf(fmaxf(py, 0.f), 37.f);
        float fl = floorf(py);
        float ql = fminf(fmaxf(fl, 0.f), 37.f);
        float qr = fminf(fmaxf(fl + 1.f, 0.f), 37.f);
        s_qyl[tid] = (int)ql; s_qyr[tid] = (int)qr;
        s_gyl[tid] = 1.f + (ql - pc);
        s_gyr[tid] = 1.f - (qr - pc);
    }

    // row-interpolated values: xrow[c(64)][i(3)*38 + col(38)], pitch 115
    __shared__ float xrow[64 * 115];

    const float* xb = x + (size_t)(b * CT + c0) * (HH * WW);

#pragma unroll
    for (int i = 0; i < 3; ++i) {
        const int rl = qxl[i], rr = qxr[i];
        const float gl = gxl[i], gr = gxr[i];
        const bool lok = (rl >= 1 && rl <= 36);
        const bool rok = (rr >= 1 && rr <= 36);
        for (int e = tid; e < 64 * 38; e += 256) {
            int c = e / 38;
            int col = e - c * 38;            // padded col 0..37
            float vl = 0.f, vr = 0.f;
            if (col >= 1 && col <= 36) {
                const float* xc = xb + c * (HH * WW);
                if (lok) vl = xc[(rl - 1) * WW + (col - 1)];
                if (rok) vr = xc[(rr - 1) * WW + (col - 1)];
            }
            xrow[c * 115 + i * 38 + col] = gl * vl + gr * vr;
        }
    }
    __syncthreads();

    // write phase: thread (xi, cg) -> 9 taps x 4 channels, 8B stores
    for (int e = tid; e < 16 * 36; e += 256) {
        const int xi = e >> 4;
        const int cg = e & 15;
        float gl[3], gr[3]; int ql[3], qr[3];
#pragma unroll
        for (int j = 0; j < 3; ++j) {
            int t = xi * 3 + j;
            gl[j] = s_gyl[t]; gr[j] = s_gyr[t];
            ql[j] = s_qyl[t]; qr[j] = s_qyr[t];
        }
        const size_t obase = ((size_t)b * NP + y * WW + xi) * KK + c0 + cg * 4;
#pragma unroll
        for (int n = 0; n < 9; ++n) {
            const int i = n / 3, j = n % 3;
            us4 o;
#pragma unroll
            for (int cc = 0; cc < 4; ++cc) {
                const float* xr = &xrow[(cg * 4 + cc) * 115 + i * 38];
                float v = gl[j] * xr[ql[j]] + gr[j] * xr[qr[j]];
                o[cc] = f2bf(v);
            }
            *reinterpret_cast<us4*>(xt + obase + n * 256) = o;
        }
    }
}

// ---------------- kernel 3: MFMA GEMM, 128x128 tile, BK=64, 4 waves ---------------
__global__ __launch_bounds__(256) void gemm_kernel(const unsigned short* __restrict__ wbf,
                                                   const unsigned short* __restrict__ xt,
                                                   float* __restrict__ out) {
    const int bx = blockIdx.x;        // 16 * 2 * 11 = 352 blocks
    const int b = bx / 22;
    const int rem = bx % 22;
    const int mt = rem / 11;
    const int nt = rem % 11;
    const int m0 = mt * 128;
    const int p0 = nt * 128;
    const int g = b & 3;
    const int mimg = b >> 2;

    const unsigned short* Ab = wbf + (size_t)(g * OUTG + m0) * KK;
    const unsigned short* Bb = xt + (size_t)b * NP * KK;

    __shared__ __align__(16) unsigned short As[128 * 64];
    __shared__ __align__(16) unsigned short Bs[128 * 64];

    const int tid = threadIdx.x;
    const int wave = tid >> 6, lane = tid & 63;
    const int wr = wave >> 1, wc = wave & 1;
    const int l8 = lane >> 3, ls = lane & 7;

    f32x4 acc[4][4] = {};

    for (int kt = 0; kt < 36; ++kt) {
        const int k0 = kt * 64;
        __syncthreads();
#pragma unroll
        for (int ii = 0; ii < 4; ++ii) {
            int inst = wave * 4 + ii;
            int row = inst * 8 + l8;                       // 0..127
            const unsigned short* srcA = Ab + (size_t)row * KK + k0 + ls * 8;
            __builtin_amdgcn_global_load_lds(
                (const __attribute__((address_space(1))) void*)srcA,
                (__attribute__((address_space(3))) void*)&As[inst * 512], 16, 0, 0);
            int prow = p0 + inst * 8 + l8;
            prow = prow < NP ? prow : NP - 1;              // clamp edge tile (masked at store)
            const unsigned short* srcB = Bb + (size_t)prow * KK + k0 + ls * 8;
            __builtin_amdgcn_global_load_lds(
                (const __attribute__((address_space(1))) void*)srcB,
                (__attribute__((address_space(3))) void*)&Bs[inst * 512], 16, 0, 0);
        }
        __syncthreads();
#pragma unroll
        for (int kk = 0; kk < 2; ++kk) {
            short8 a[4], bfr[4];
            const int krd = kk * 32 + (lane >> 4) * 8;
            const int rA = wr * 64 + (lane & 15);
            const int rB = wc * 64 + (lane & 15);
#pragma unroll
            for (int m = 0; m < 4; ++m)
                a[m] = *(const short8*)&As[(rA + m * 16) * 64 + krd];
#pragma unroll
            for (int n = 0; n < 4; ++n)
                bfr[n] = *(const short8*)&Bs[(rB + n * 16) * 64 + krd];
#pragma unroll
            for (int m = 0; m < 4; ++m)
#pragma unroll
                for (int n = 0; n < 4; ++n)
                    acc[m][n] = __builtin_amdgcn_mfma_f32_16x16x32_bf16(
                        a[m], bfr[n], acc[m][n], 0, 0, 0);
        }
    }

    float* ob = out + ((size_t)mimg * OCH + g * OUTG) * NP;
    const int o0 = m0 + wr * 64 + ((lane >> 4) << 2);
    const int pc = p0 + wc * 64 + (lane & 15);
#pragma unroll
    for (int n = 0; n < 4; ++n) {
        int p = pc + n * 16;
        if (p >= NP) continue;
#pragma unroll
        for (int m = 0; m < 4; ++m) {
#pragma unroll
            for (int r = 0; r < 4; ++r)
                ob[(size_t)(o0 + m * 16 + r) * NP + p] = acc[m][n][r];
        }
    }
}

extern "C" void kernel_launch(void* const* d_in, const int* in_sizes, int n_in,
                              void* d_out, int out_size, void* d_ws, size_t ws_size,
                              hipStream_t stream) {
    const float* x   = (const float*)d_in[0];
    const float* tf  = (const float*)d_in[1];
    const float* off = (const float*)d_in[2];
    float* out = (float*)d_out;

    unsigned short* xt  = (unsigned short*)d_ws;                    // [16][1296][2304] bf16
    unsigned short* wbf = xt + (size_t)NB * NP * KK;                // [1024][2304] bf16

    hipLaunchKernelGGL(cvt_filter, dim3(OCH), dim3(256), 0, stream, tf, wbf);
    hipLaunchKernelGGL(sample_kernel, dim3(NB * 4 * HH), dim3(256), 0, stream, x, off, xt);
    hipLaunchKernelGGL(gemm_kernel, dim3(352), dim3(256), 0, stream, wbf, xt, out);
}

// Round 3
// 80.764 us; speedup vs baseline: 1.7339x; 1.2765x over previous
//
#include <hip/hip_runtime.h>
#include <hip/hip_bf16.h>

// DeformConv2d: x[4,4,256,36,36] f32, filter[1024,256,3,3] f32, offset[16,2] f32
// out[4,1024,36,36] f32.
// K-axis layout (both operands, opaque to GEMM): k' = n*256 + c  (tap-major).
// GEMM R3: 128x64 tiles (grid 672 = 2.6 blk/CU), LDS double-buffer w/ stage-early
// 2-phase pipeline, T2 XOR-swizzle (pre-swizzled gload_lds source + swizzled read),
// XCD-bijective block swizzle grouping all tiles of one b per XCD.
// ws: xt [16][1296][2304] bf16 + w' [1024][2304] bf16 = 100,270,080 B.

#define HH 36
#define WW 36
#define CT 256
#define NB 16
#define KK 2304      // 9*256
#define NP 1296      // 36*36
#define OCH 1024
#define OUTG 256

typedef __attribute__((ext_vector_type(8))) short short8;
typedef __attribute__((ext_vector_type(4))) float f32x4;
typedef __attribute__((ext_vector_type(4))) unsigned short us4;

__device__ __forceinline__ unsigned short f2bf(float v) {
    unsigned u = __float_as_uint(v);
    u += 0x7fffu + ((u >> 16) & 1u);   // RNE
    return (unsigned short)(u >> 16);
}

// ---------------- kernel 1: filter fp32 [o][c*9+n] -> bf16 [o][n*256+c] ----------
__global__ __launch_bounds__(256) void cvt_filter(const float* __restrict__ f,
                                                  unsigned short* __restrict__ w) {
    const int o = blockIdx.x;
    const float* fo = f + (size_t)o * KK;
    unsigned short* wo = w + (size_t)o * KK;
    for (int k4 = threadIdx.x * 4; k4 < KK; k4 += 1024) {
        int n = k4 >> 8;          // tap
        int c = k4 & 255;         // channel (multiple of 4)
        us4 v;
#pragma unroll
        for (int cc = 0; cc < 4; ++cc) v[cc] = f2bf(fo[(c + cc) * 9 + n]);
        *reinterpret_cast<us4*>(wo + k4) = v;
    }
}

// ---------------- kernel 2: deformable bilinear sampling -> Xoff^T bf16 -----------
// grid 2304 = 16b * 4chunk * 36y (XCD-swizzled); block handles 64 channels, one y.
__global__ __launch_bounds__(256) void sample_kernel(const float* __restrict__ x,
                                                     const float* __restrict__ off,
                                                     unsigned short* __restrict__ xt) {
    const int wid = (blockIdx.x & 7) * 288 + (blockIdx.x >> 3);
    const int b = wid / 144;
    const int rem = wid - b * 144;
    const int chunk = rem / 36;
    const int y = rem - chunk * 36;
    const int c0 = chunk * 64;
    const int tid = threadIdx.x;
    const float sx = 3.0f / off[2 * b + 0];
    const float sy = 3.0f / off[2 * b + 1];

    int qxl[3], qxr[3]; float gxl[3], gxr[3];
#pragma unroll
    for (int i = 0; i < 3; ++i) {
        float px = (float)(y + 1) + (float)(i - 1) * sx;
        float pc = fminf(fmaxf(px, 0.f), 37.f);
        float fl = floorf(px);
        float ql = fminf(fmaxf(fl, 0.f), 37.f);
        float qr = fminf(fmaxf(fl + 1.f, 0.f), 37.f);
        qxl[i] = (int)ql; qxr[i] = (int)qr;
        gxl[i] = 1.f + (ql - pc);
        gxr[i] = 1.f - (qr - pc);
    }

    __shared__ int   s_qyl[HH * 3], s_qyr[HH * 3];
    __shared__ float s_gyl[HH * 3], s_gyr[HH * 3];
    if (tid < HH * 3) {
        int xx = tid / 3, j = tid % 3;
        float py = (float)(xx + 1) + (float)(j - 1) * sy;
        float pc = fminf(fmaxf(py, 0.f), 37.f);
        float fl = floorf(py);
        float ql = fminf(fmaxf(fl, 0.f), 37.f);
        float qr = fminf(fmaxf(fl + 1.f, 0.f), 37.f);
        s_qyl[tid] = (int)ql; s_qyr[tid] = (int)qr;
        s_gyl[tid] = 1.f + (ql - pc);
        s_gyr[tid] = 1.f - (qr - pc);
    }

    __shared__ float xrow[64 * 115];   // [c][i*38+col], pitch 115

    const float* xb = x + (size_t)(b * CT + c0) * (HH * WW);

#pragma unroll
    for (int i = 0; i < 3; ++i) {
        const int rl = qxl[i], rr = qxr[i];
        const float gl = gxl[i], gr = gxr[i];
        const bool lok = (rl >= 1 && rl <= 36);
        const bool rok = (rr >= 1 && rr <= 36);
        for (int e = tid; e < 64 * 38; e += 256) {
            int c = e / 38;
            int col = e - c * 38;
            float vl = 0.f, vr = 0.f;
            if (col >= 1 && col <= 36) {
                const float* xc = xb + c * (HH * WW);
                if (lok) vl = xc[(rl - 1) * WW + (col - 1)];
                if (rok) vr = xc[(rr - 1) * WW + (col - 1)];
            }
            xrow[c * 115 + i * 38 + col] = gl * vl + gr * vr;
        }
    }
    __syncthreads();

    for (int e = tid; e < 16 * 36; e += 256) {
        const int xi = e >> 4;
        const int cg = e & 15;
        float gl[3], gr[3]; int ql[3], qr[3];
#pragma unroll
        for (int j = 0; j < 3; ++j) {
            int t = xi * 3 + j;
            gl[j] = s_gyl[t]; gr[j] = s_gyr[t];
            ql[j] = s_qyl[t]; qr[j] = s_qyr[t];
        }
        const size_t obase = ((size_t)b * NP + y * WW + xi) * KK + c0 + cg * 4;
#pragma unroll
        for (int n = 0; n < 9; ++n) {
            const int i = n / 3, j = n % 3;
            us4 o;
#pragma unroll
            for (int cc = 0; cc < 4; ++cc) {
                const float* xr = &xrow[(cg * 4 + cc) * 115 + i * 38];
                float v = gl[j] * xr[ql[j]] + gr[j] * xr[qr[j]];
                o[cc] = f2bf(v);
            }
            *reinterpret_cast<us4*>(xt + obase + n * 256) = o;
        }
    }
}

// ---------------- kernel 3: MFMA GEMM, 128x64 tile, BK=64, dbuf, swizzled ---------
__global__ __launch_bounds__(256) void gemm_kernel(const unsigned short* __restrict__ wbf,
                                                   const unsigned short* __restrict__ xt,
                                                   float* __restrict__ out) {
    // 672 blocks = 8 XCD * 84; 84 per XCD = 2 b's worth (42 tiles per b)
    const int wid = (blockIdx.x & 7) * 84 + (blockIdx.x >> 3);
    const int b = wid / 42;
    const int rem = wid - b * 42;
    const int mt = rem / 21;
    const int nt = rem - mt * 21;
    const int m0 = mt * 128;
    const int p0 = nt * 64;
    const int g = b & 3;
    const int mimg = b >> 2;

    const unsigned short* Ab = wbf + (size_t)(g * OUTG + m0) * KK;
    const unsigned short* Bb = xt + (size_t)b * NP * KK;

    __shared__ __align__(16) unsigned short As[2][128 * 64];
    __shared__ __align__(16) unsigned short Bs[2][64 * 64];

    const int tid = threadIdx.x;
    const int wave = tid >> 6, lane = tid & 63;
    const int wr = wave >> 1, wc = wave & 1;
    const int l8 = lane >> 3;                 // staging sub-row 0..7
    const int sgrp = (lane & 7) ^ l8;         // pre-swizzled source column group

    f32x4 acc[4][2] = {};

    // staging: A rows 0..127 (16 wave-instr), B rows 0..63 (8 wave-instr)
#define STAGE(BUF, KT) do {                                                       \
    const int k0_ = (KT) * 64;                                                    \
    _Pragma("unroll")                                                             \
    for (int ii = 0; ii < 4; ++ii) {                                              \
        const int inst = wave * 4 + ii;                                           \
        const int row = inst * 8 + l8;                                            \
        const unsigned short* srcA = Ab + (size_t)row * KK + k0_ + sgrp * 8;      \
        __builtin_amdgcn_global_load_lds(                                         \
            (const __attribute__((address_space(1))) void*)srcA,                  \
            (__attribute__((address_space(3))) void*)&As[BUF][inst * 512], 16, 0, 0); \
    }                                                                             \
    _Pragma("unroll")                                                             \
    for (int ii = 0; ii < 2; ++ii) {                                              \
        const int inst = wave * 2 + ii;                                           \
        const int row = inst * 8 + l8;                                            \
        int prow = p0 + row;                                                      \
        prow = prow < NP ? prow : NP - 1;                                         \
        const unsigned short* srcB = Bb + (size_t)prow * KK + k0_ + sgrp * 8;     \
        __builtin_amdgcn_global_load_lds(                                         \
            (const __attribute__((address_space(1))) void*)srcB,                  \
            (__attribute__((address_space(3))) void*)&Bs[BUF][inst * 512], 16, 0, 0); \
    }                                                                             \
} while (0)

#define COMPUTE(BUF) do {                                                         \
    _Pragma("unroll")                                                             \
    for (int kk = 0; kk < 2; ++kk) {                                              \
        short8 a[4], bfr[2];                                                      \
        const int g8 = (((kk * 4) + (lane >> 4)) ^ (lane & 7)) << 3;              \
        const int rA = wr * 64 + (lane & 15);                                     \
        const int rB = wc * 32 + (lane & 15);                                     \
        _Pragma("unroll")                                                         \
        for (int m = 0; m < 4; ++m)                                               \
            a[m] = *(const short8*)&As[BUF][(rA + m * 16) * 64 + g8];             \
        _Pragma("unroll")                                                         \
        for (int n = 0; n < 2; ++n)                                               \
            bfr[n] = *(const short8*)&Bs[BUF][(rB + n * 16) * 64 + g8];           \
        _Pragma("unroll")                                                         \
        for (int m = 0; m < 4; ++m)                                               \
            _Pragma("unroll")                                                     \
            for (int n = 0; n < 2; ++n)                                           \
                acc[m][n] = __builtin_amdgcn_mfma_f32_16x16x32_bf16(              \
                    a[m], bfr[n], acc[m][n], 0, 0, 0);                            \
    }                                                                             \
} while (0)

    STAGE(0, 0);
    __syncthreads();                 // compiler emits vmcnt(0) drain before barrier

    int cur = 0;
#pragma unroll 1
    for (int kt = 0; kt < 35; ++kt) {
        STAGE(cur ^ 1, kt + 1);      // issue next-tile loads first (fly under MFMA)
        COMPUTE(cur);
        __syncthreads();             // drains vmcnt(0)+lgkmcnt(0): next tile ready
        cur ^= 1;
    }
    COMPUTE(cur);

#undef STAGE
#undef COMPUTE

    float* ob = out + ((size_t)mimg * OCH + g * OUTG) * NP;
    const int o0 = m0 + wr * 64 + ((lane >> 4) << 2);
    const int pc = p0 + wc * 32 + (lane & 15);
#pragma unroll
    for (int n = 0; n < 2; ++n) {
        int p = pc + n * 16;
        if (p >= NP) continue;
#pragma unroll
        for (int m = 0; m < 4; ++m) {
#pragma unroll
            for (int r = 0; r < 4; ++r)
                ob[(size_t)(o0 + m * 16 + r) * NP + p] = acc[m][n][r];
        }
    }
}

extern "C" void kernel_launch(void* const* d_in, const int* in_sizes, int n_in,
                              void* d_out, int out_size, void* d_ws, size_t ws_size,
                              hipStream_t stream) {
    const float* x   = (const float*)d_in[0];
    const float* tf  = (const float*)d_in[1];
    const float* off = (const float*)d_in[2];
    float* out = (float*)d_out;

    unsigned short* xt  = (unsigned short*)d_ws;                    // [16][1296][2304] bf16
    unsigned short* wbf = xt + (size_t)NB * NP * KK;                // [1024][2304] bf16

    hipLaunchKernelGGL(cvt_filter, dim3(OCH), dim3(256), 0, stream, tf, wbf);
    hipLaunchKernelGGL(sample_kernel, dim3(NB * 4 * HH), dim3(256), 0, stream, x, off, xt);
    hipLaunchKernelGGL(gemm_kernel, dim3(672), dim3(256), 0, stream, wbf, xt, out);
}